// Round 8
// baseline (696.151 us; speedup 1.0000x reference)
//
#include <hip/hip_runtime.h>
#include <math.h>

// Problem constants
#define N_ROWS 8192
#define M_COLS 2048
#define K_DIM  1024
#define NM     ((size_t)N_ROWS * M_COLS)

#define LAM       0.9090909090909091f         // GAMMA/(GAMMA+EPS)
#define LOG_M     7.624618986159398f          // log(2048)

#define SKB 1024                               // sinkhorn blocks (exactly 4/CU)
#define RPB (N_ROWS / SKB)                     // 8 rows per block

typedef __bf16 bf16x8 __attribute__((ext_vector_type(8)));
typedef float  f32x4  __attribute__((ext_vector_type(4)));
typedef unsigned short u16x8 __attribute__((ext_vector_type(8)));
typedef _Float16 h8 __attribute__((ext_vector_type(8)));

// d_out memory map (64 MB):
//   row r (r<8192): bytes [r*8192, r*8192+4096)  = cost fp16 row r (2048 halves)
//                   bytes [r*8192+4096, r*8192+8192) = "hole"
//   Xb bf16 row i (16 MB): hole i>>1, slot i&1  -> byte (i>>1)*8192 + 4096 + (i&1)*2048
//   Yb bf16 row j ( 4 MB): hole 4096+(j>>1)     -> byte 32MB + (j>>1)*8192 + 4096 + (j&1)*2048
//
// LESSONS LEDGER:
//  r4: same-line fp32 atomicAdds at depth 512 = ~120us serialized RMWs.
//      Keep atomic depth <= ~16 per address everywhere (sub-counters, dpart).
//  r6: counted-vmcnt 3-buffer at 128^2 tile regresses (occupancy+FETCH).
//  r7: four different sk-phase structures all ~150us => cost is the SERIAL
//      DISPATCH CHAIN (7 launches, 4x re-read of 32MB cost), not internals.
//  r8: persistent sk_all: 1024 blocks (=256CUx4 guaranteed resident), manual
//      sense-free grid barrier (64 sub-counters 16-deep + collector + gen),
//      threadfence release/acquire for cross-XCD visibility. E in registers.

static __device__ __forceinline__ size_t xb_off(int i) {
    return ((size_t)(i >> 1) << 13) + 4096 + ((size_t)(i & 1) << 11);
}
static __device__ __forceinline__ size_t yb_off(int j) {
    return ((size_t)1 << 25) + ((size_t)(j >> 1) << 13) + 4096 + ((size_t)(j & 1) << 11);
}

// ---------------------------------------------------------------------------
// fp32 pair -> packed bf16 (RNE)
// ---------------------------------------------------------------------------
static __device__ __forceinline__ unsigned pk_bf16(float a, float b) {
#if __has_builtin(__builtin_amdgcn_cvt_pk_bf16_f32)
    typedef __bf16 bf16x2 __attribute__((ext_vector_type(2)));
    bf16x2 r = __builtin_amdgcn_cvt_pk_bf16_f32(a, b);
    return __builtin_bit_cast(unsigned, r);
#else
    unsigned ua = __float_as_uint(a), ub = __float_as_uint(b);
    ua += 0x7FFFu + ((ua >> 16) & 1u);
    ub += 0x7FFFu + ((ub >> 16) & 1u);
    return (ua >> 16) | (ub & 0xFFFF0000u);
#endif
}

static __device__ __forceinline__ bf16x8 lds_frag(const unsigned short* p) {
    return __builtin_bit_cast(bf16x8, *(const u16x8*)p);
}

static __device__ __forceinline__ void gload16(const void* g, void* l) {
    __builtin_amdgcn_global_load_lds(
        (const __attribute__((address_space(1))) unsigned int*)g,
        (__attribute__((address_space(3))) unsigned int*)l, 16, 0, 0);
}

// ---------------------------------------------------------------------------
// per-row stats (min, sum, ||a-min||^2) + bf16 conversion into d_out holes.
// Block 0 additionally zeroes params/sigma/sync-state/d2max/dist each launch.
// ---------------------------------------------------------------------------
__global__ __launch_bounds__(256) void rowstats_cvt(
    const float* __restrict__ X, const float* __restrict__ Y,
    unsigned char* __restrict__ outb,
    const int* __restrict__ iters, const int* __restrict__ ipe,
    float* __restrict__ params, float* __restrict__ sigma,
    unsigned int* __restrict__ zbuf,          // ws+16: subcnt[64],gen,pad,dpart[64]
    unsigned int* __restrict__ d2max, float* __restrict__ dist,
    float* __restrict__ mx, float* __restrict__ sx, float* __restrict__ x2,
    float* __restrict__ my, float* __restrict__ sy, float* __restrict__ y2)
{
    const int b = blockIdx.x, tid = threadIdx.x;

    if (b == 0) {
        #pragma unroll 1
        for (int i = tid; i < 3 * M_COLS; i += 256) sigma[i] = 0.0f;
        if (tid < 144) zbuf[tid] = 0u;        // subcnt+gen+pad+dpart
        if (tid == 0) {
            float ramp = 10.0f * (float)ipe[0];
            float rho;
            if (ramp == 0.0f) {
                rho = 1.1f;
            } else {
                float cur = fminf(fmaxf((float)iters[0], 0.0f), ramp);
                float phase = 1.0f - cur / ramp;
                rho = expf(-5.0f * phase * phase) + 0.1f;
            }
            rho = fminf(rho, 1.0f);
            params[0] = rho;
            params[1] = logf(rho) - LOG_M;   // logb = log(rho/M)
            *d2max = 0u;
            *dist = 0.0f;
        }
    }

    const bool isX = b < N_ROWS;
    const int row = isX ? b : b - N_ROWS;
    const float* src = isX ? (X + (size_t)row * K_DIM) : (Y + (size_t)row * K_DIM);
    const float4 v = ((const float4*)src)[tid];

    uint2 p; p.x = pk_bf16(v.x, v.y); p.y = pk_bf16(v.z, v.w);
    size_t off = isX ? xb_off(row) : yb_off(row);
    *(uint2*)(outb + off + (size_t)tid * 8) = p;

    float lmin = fminf(fminf(v.x, v.y), fminf(v.z, v.w));
    float lsum = v.x + v.y + v.z + v.w;
    float lsq  = v.x*v.x + v.y*v.y + v.z*v.z + v.w*v.w;

    __shared__ float rmin[256], rsum[256], rsq[256];
    rmin[tid] = lmin; rsum[tid] = lsum; rsq[tid] = lsq;
    __syncthreads();
    for (int s = 128; s > 0; s >>= 1) {
        if (tid < s) {
            rmin[tid] = fminf(rmin[tid], rmin[tid + s]);
            rsum[tid] += rsum[tid + s];
            rsq[tid]  += rsq[tid + s];
        }
        __syncthreads();
    }
    if (tid == 0) {
        float m = rmin[0], s = rsum[0], q = rsq[0];
        if (isX) { mx[row] = m; sx[row] = s; x2[row] = q - 2.f*m*s + (float)K_DIM*m*m; }
        else     { my[row] = m; sy[row] = s; y2[row] = q - 2.f*m*s + (float)K_DIM*m*m; }
    }
}

// ---------------------------------------------------------------------------
// MFMA GEMM on pre-converted bf16 + cost epilogue (fp16 store).
// 128x128 tile, 4 waves, BK=32, 2-phase double-buffer, XCD swizzle.
// (round-1 verified — 57.4us; do not touch)
// ---------------------------------------------------------------------------
__global__ __launch_bounds__(256, 4) void gemm_cost_mfma(
    float* __restrict__ gbuf,
    const float* __restrict__ mx, const float* __restrict__ sx, const float* __restrict__ x2,
    const float* __restrict__ my, const float* __restrict__ sy, const float* __restrict__ y2,
    unsigned int* __restrict__ d2max)
{
    __shared__ unsigned short Ash[2][128 * 32];
    __shared__ unsigned short Bsh[2][128 * 32];
    __shared__ float rmax[256];

    const unsigned char* outb = (const unsigned char*)gbuf;
    const int tid   = threadIdx.x;
    const int lane  = tid & 63;
    const int wave  = tid >> 6;
    const int wi    = wave >> 1;
    const int wj    = wave & 1;
    const int row16 = lane & 15;
    const int quad  = lane >> 4;

    const int bid0 = blockIdx.y * 16 + blockIdx.x;
    const int bid  = (bid0 & 7) * 128 + (bid0 >> 3);
    const int i0 = (bid >> 4) * 128, j0 = (bid & 15) * 128;

    const int chA = (lane & 3) * 16;
    const unsigned char* pa[2];
    const unsigned char* pb[2];
    unsigned short* laA[2];
    unsigned short* lbB[2];
    #pragma unroll
    for (int p = 0; p < 2; ++p) {
        const int rt = (p * 4 + wave) * 16 + (lane >> 2);
        pa[p] = outb + xb_off(i0 + rt) + chA;
        pb[p] = outb + yb_off(j0 + rt) + chA;
        laA[p] = &Ash[0][(p * 4 + wave) * 512];
        lbB[p] = &Bsh[0][(p * 4 + wave) * 512];
    }

    f32x4 acc[4][4];
    #pragma unroll
    for (int u = 0; u < 4; ++u)
        #pragma unroll
        for (int v = 0; v < 4; ++v) acc[u][v] = (f32x4){0.f, 0.f, 0.f, 0.f};

#define STAGE(nb) do {                                        \
        gload16(pa[0], laA[0] + (nb) * 4096);                 \
        gload16(pa[1], laA[1] + (nb) * 4096);                 \
        gload16(pb[0], lbB[0] + (nb) * 4096);                 \
        gload16(pb[1], lbB[1] + (nb) * 4096);                 \
        pa[0] += 64; pa[1] += 64; pb[0] += 64; pb[1] += 64;   \
    } while (0)

#define COMPUTE(cb) do {                                                         \
        bf16x8 af[4], bfr[4];                                                    \
        _Pragma("unroll")                                                        \
        for (int t = 0; t < 4; ++t) {                                            \
            af[t]  = lds_frag(&Ash[cb][(wi * 64 + t * 16 + row16) * 32 + quad * 8]); \
            bfr[t] = lds_frag(&Bsh[cb][(wj * 64 + t * 16 + row16) * 32 + quad * 8]); \
        }                                                                        \
        _Pragma("unroll")                                                        \
        for (int ti = 0; ti < 4; ++ti)                                           \
            _Pragma("unroll")                                                    \
            for (int tj = 0; tj < 4; ++tj)                                       \
                acc[ti][tj] = __builtin_amdgcn_mfma_f32_16x16x32_bf16(           \
                    af[ti], bfr[tj], acc[ti][tj], 0, 0, 0);                      \
    } while (0)

    STAGE(0);
    __syncthreads();

#pragma unroll 1
    for (int it = 0; it < 15; ++it) {
        STAGE(1); COMPUTE(0); __syncthreads();
        STAGE(0); COMPUTE(1); __syncthreads();
    }
    STAGE(1); COMPUTE(0); __syncthreads();
    COMPUTE(1);

#undef STAGE
#undef COMPUTE

    _Float16* costh = (_Float16*)gbuf;
    float lmax = 0.0f;
    float myj[4], syj[4], yy[4];
    #pragma unroll
    for (int tj = 0; tj < 4; ++tj) {
        const int j = j0 + wj * 64 + tj * 16 + row16;
        myj[tj] = my[j]; syj[tj] = sy[j]; yy[tj] = y2[j];
    }
    #pragma unroll
    for (int ti = 0; ti < 4; ++ti) {
        #pragma unroll
        for (int reg = 0; reg < 4; ++reg) {
            const int i = i0 + wi * 64 + ti * 16 + quad * 4 + reg;
            const float mxi = mx[i], sxi = sx[i], xxi = x2[i];
            #pragma unroll
            for (int tj = 0; tj < 4; ++tj) {
                const int j = j0 + wj * 64 + tj * 16 + row16;
                float corr = mxi * syj[tj] + myj[tj] * sxi - (float)K_DIM * mxi * myj[tj];
                float d2 = xxi + yy[tj] - 2.0f * acc[ti][tj][reg] + 2.0f * corr;
                d2 = fmaxf(d2, 0.0f);
                lmax = fmaxf(lmax, d2);
                costh[(size_t)i * 4096 + j] = (_Float16)sqrtf(d2);
            }
        }
    }
    rmax[tid] = lmax;
    __syncthreads();
    for (int s = 128; s > 0; s >>= 1) {
        if (tid < s) rmax[tid] = fmaxf(rmax[tid], rmax[tid + s]);
        __syncthreads();
    }
    if (tid == 0) atomicMax(d2max, __float_as_uint(rmax[0]));
}

// ---------------------------------------------------------------------------
// Persistent fused sinkhorn + flow + dist. 1024 blocks x 256 thr = exactly
// 4 blocks/CU x 256 CU (residency guaranteed: VGPR capped 128 by
// launch_bounds, LDS ~2KB) -> manual grid barrier is deadlock-free.
// Barrier: 64 sub-counters (16-deep atomics) -> collector block 0 polls,
// bumps gen; all spin on gen. threadfence = agent release/acquire
// (L2 writeback / invalidate) makes plain gpart/sigma stores visible
// across XCDs. Counters zeroed by rowstats each launch.
// ---------------------------------------------------------------------------
__global__ __launch_bounds__(256, 4) void sk_all(
    float* __restrict__ outbuf, float* __restrict__ sigma,
    _Float16* __restrict__ gpart,
    unsigned int* __restrict__ subcnt, unsigned int* __restrict__ gen,
    float* __restrict__ dpart, float* __restrict__ dist,
    const float* __restrict__ params, const unsigned int* __restrict__ d2max)
{
    __shared__ float R[RPB][4];
    __shared__ float W[RPB];
    __shared__ float R2[4][32];
    __shared__ float red[256];

    const int tid  = threadIdx.x;
    const int lane = tid & 63;
    const int wave = tid >> 6;
    const int bx   = blockIdx.x;
    const int r0   = bx * RPB;
    const float logb = params[1];
    const float invC10 = 10.0f * rsqrtf(__uint_as_float(*d2max));

#define GRIDBAR(BNUM) do {                                                     \
        __syncthreads();                                                       \
        if (tid == 0) {                                                        \
            __threadfence();                                                   \
            atomicAdd(&subcnt[bx & 63], 1u);                                   \
        }                                                                      \
        if (bx == 0) {                                                         \
            if (tid < 64) {                                                    \
                const unsigned tgt = (unsigned)(BNUM) * (SKB / 64);            \
                while (__hip_atomic_load(&subcnt[tid], __ATOMIC_RELAXED,       \
                                         __HIP_MEMORY_SCOPE_AGENT) < tgt)      \
                    __builtin_amdgcn_s_sleep(1);                               \
            }                                                                  \
            __syncthreads();                                                   \
            if (tid == 0) { __threadfence(); atomicAdd(gen, 1u); }             \
        }                                                                      \
        if (tid == 0) {                                                        \
            while (__hip_atomic_load(gen, __ATOMIC_RELAXED,                    \
                                     __HIP_MEMORY_SCOPE_AGENT) < (unsigned)(BNUM)) \
                __builtin_amdgcn_s_sleep(1);                                   \
            __threadfence();                                                   \
        }                                                                      \
        __syncthreads();                                                       \
    } while (0)

    // E = fp16(exp(-cost*10/cmax)) in registers: 8 rows x 8 cols/thread
    // (32 VGPRs; r7-identical numerics). Cost is read from global ONCE.
    const _Float16* Cb = (const _Float16*)outbuf;
    h8 E[RPB];
    #pragma unroll
    for (int r = 0; r < RPB; ++r) {
        h8 c = __builtin_bit_cast(h8, *(const uint4*)(Cb + (size_t)(r0 + r) * 4096 + 8 * tid));
        h8 e;
        #pragma unroll
        for (int k = 0; k < 8; ++k)
            e[k] = (_Float16)__expf(-(float)c[k] * invC10);
        E[r] = e;
    }

    float u8[8];
    #pragma unroll
    for (int k = 0; k < 8; ++k) u8[k] = 1.0f;

    #pragma unroll 1
    for (int it = 0; it < 3; ++it) {
        // pass A: row sums t_r -> w_r
        float pr[RPB];
        #pragma unroll
        for (int r = 0; r < RPB; ++r) {
            float s = 0.0f;
            #pragma unroll
            for (int k = 0; k < 8; ++k) s += (float)E[r][k] * u8[k];
            pr[r] = s;
        }
        #pragma unroll
        for (int r = 0; r < RPB; ++r)
            #pragma unroll
            for (int off = 32; off > 0; off >>= 1)
                pr[r] += __shfl_xor(pr[r], off, 64);
        if (lane == 0)
            #pragma unroll
            for (int r = 0; r < RPB; ++r) R[r][wave] = pr[r];
        __syncthreads();
        if (tid < RPB) {
            float t = R[tid][0] + R[tid][1] + R[tid][2] + R[tid][3];
            W[tid] = __expf(-LAM * (logb + __logf(t)));
        }
        __syncthreads();

        // pass B: column partials -> coalesced fp16 stores to gpart
        float p[8] = {0.f, 0.f, 0.f, 0.f, 0.f, 0.f, 0.f, 0.f};
        #pragma unroll
        for (int r = 0; r < RPB; ++r) {
            const float wr = W[r];
            #pragma unroll
            for (int k = 0; k < 8; ++k) p[k] += (float)E[r][k] * wr;
        }
        h8 ph;
        #pragma unroll
        for (int k = 0; k < 8; ++k) ph[k] = (_Float16)p[k];
        *(uint4*)(gpart + (size_t)bx * M_COLS + 8 * tid) = __builtin_bit_cast(uint4, ph);

        GRIDBAR(2 * it + 1);

        // blocks 0..63: reduce 32 cols each over 1024 partials -> sigma[it]
        float* sg = sigma + it * M_COLS;
        if (bx < 64) {
            const int c0  = bx * 32;
            const int col = tid & 31;
            const int slc = tid >> 5;          // 0..7, 128 rows each
            float s = 0.0f;
            #pragma unroll 4
            for (int rr = slc * 128; rr < slc * 128 + 128; ++rr)
                s += (float)gpart[(size_t)rr * M_COLS + c0 + col];
            s += __shfl_xor(s, 32, 64);        // merge slice pairs in wave
            if (lane < 32) R2[wave][col] = s;
            __syncthreads();
            if (tid < 32)
                sg[c0 + tid] = R2[0][tid] + R2[1][tid] + R2[2][tid] + R2[3][tid];
        }

        GRIDBAR(2 * it + 2);

        const float4 sa = *(const float4*)(sg + 8 * tid);
        const float4 sb = *(const float4*)(sg + 8 * tid + 4);
        u8[0] = (float)N_ROWS / sa.x; u8[1] = (float)N_ROWS / sa.y;
        u8[2] = (float)N_ROWS / sa.z; u8[3] = (float)N_ROWS / sa.w;
        u8[4] = (float)N_ROWS / sb.x; u8[5] = (float)N_ROWS / sb.y;
        u8[6] = (float)N_ROWS / sb.z; u8[7] = (float)N_ROWS / sb.w;
    }

    // flow = E * w_r * u_j / (N*M); cn = -0.1*ln(E)  (round-1 verified path)
    const float invNM = 1.0f / ((float)N_ROWS * (float)M_COLS);
    float local = 0.0f;
    #pragma unroll
    for (int r = 0; r < RPB; ++r) {
        const float wr = W[r];
        float fl[8];
        #pragma unroll
        for (int k = 0; k < 8; ++k) {
            float e = (float)E[r][k];
            float o = e * wr * u8[k] * invNM;
            fl[k] = o;
            local += (-0.1f * __logf(fmaxf(e, 1e-7f))) * o;
        }
        float4 o0 = {fl[0], fl[1], fl[2], fl[3]};
        float4 o1 = {fl[4], fl[5], fl[6], fl[7]};
        float* frow = outbuf + (size_t)(r0 + r) * M_COLS + 8 * tid;
        *(float4*)frow = o0;
        *(float4*)(frow + 4) = o1;
    }

    red[tid] = local;
    __syncthreads();
    for (int s = 128; s > 0; s >>= 1) {
        if (tid < s) red[tid] += red[tid + s];
        __syncthreads();
    }
    if (tid == 0) atomicAdd(&dpart[bx & 63], red[0]);   // 16-deep per line

    GRIDBAR(7);

    if (bx == 0 && tid < 64) {
        float v = dpart[tid];
        #pragma unroll
        for (int off = 32; off > 0; off >>= 1) v += __shfl_xor(v, off, 64);
        if (tid == 0) *dist = v;
    }
#undef GRIDBAR
}

// ---------------------------------------------------------------------------
extern "C" void kernel_launch(void* const* d_in, const int* in_sizes, int n_in,
                              void* d_out, int out_size, void* d_ws, size_t ws_size,
                              hipStream_t stream)
{
    const float* x     = (const float*)d_in[0];
    const float* y     = (const float*)d_in[1];
    const int*   iters = (const int*)d_in[2];
    const int*   ipe   = (const int*)d_in[3];
    float* out = (float*)d_out;
    float* ws  = (float*)d_ws;

    // ws layout (floats): ~4.3 MB total
    float*        params = ws;                       // [0]=rho [1]=logb
    unsigned int* d2max  = (unsigned int*)(ws + 8);
    unsigned int* subcnt = (unsigned int*)(ws + 16); // 64
    unsigned int* gen    = (unsigned int*)(ws + 80); // 1 (+15 pad)
    float*        dpart  = ws + 96;                  // 64
    float* sigma = ws + 160;                         // 3 * 2048
    float* mx = sigma + 3 * M_COLS;                  // 8192
    float* sx = mx + N_ROWS;                         // 8192
    float* x2 = sx + N_ROWS;                         // 8192
    float* my = x2 + N_ROWS;                         // 2048
    float* sy = my + M_COLS;                         // 2048
    float* y2 = sy + M_COLS;                         // 2048
    _Float16* gpart = (_Float16*)(y2 + M_COLS);      // 1024*2048 fp16 = 4 MB

    float* dist = out + NM;

    rowstats_cvt<<<N_ROWS + M_COLS, 256, 0, stream>>>(
        x, y, (unsigned char*)out, iters, ipe, params, sigma, subcnt,
        d2max, dist, mx, sx, x2, my, sy, y2);
    gemm_cost_mfma<<<dim3(M_COLS / 128, N_ROWS / 128), 256, 0, stream>>>(
        out, mx, sx, x2, my, sy, y2, d2max);
    sk_all<<<SKB, 256, 0, stream>>>(
        out, sigma, gpart, subcnt, gen, dpart, dist, params, d2max);
}

// Round 9
// 208.734 us; speedup vs baseline: 3.3351x; 3.3351x over previous
//
#include <hip/hip_runtime.h>
#include <math.h>

// Problem constants
#define N_ROWS 8192
#define M_COLS 2048
#define K_DIM  1024
#define NM     ((size_t)N_ROWS * M_COLS)

#define LAM       0.9090909090909091f         // GAMMA/(GAMMA+EPS)
#define LOG_M     7.624618986159398f          // log(2048)

#define SKB 1024                               // sinkhorn blocks (4/CU resident)
#define RPB (N_ROWS / SKB)                     // 8 rows per block

typedef __bf16 bf16x8 __attribute__((ext_vector_type(8)));
typedef float  f32x4  __attribute__((ext_vector_type(4)));
typedef unsigned short u16x8 __attribute__((ext_vector_type(8)));
typedef _Float16 h8 __attribute__((ext_vector_type(8)));

// d_out memory map (64 MB):
//   row r (r<8192): bytes [r*8192, r*8192+4096)  = cost fp16 row r (2048 halves)
//                   bytes [r*8192+4096, r*8192+8192) = "hole"
//   Xb bf16 row i (16 MB): hole i>>1, slot i&1  -> byte (i>>1)*8192 + 4096 + (i&1)*2048
//   Yb bf16 row j ( 4 MB): hole 4096+(j>>1)     -> byte 32MB + (j>>1)*8192 + 4096 + (j&1)*2048
//
// LESSONS LEDGER:
//  r4: same-line fp32 atomicAdds at depth 512 = ~120us serialized RMWs.
//  r6: counted-vmcnt 3-buffer at 128^2/BK=32 regresses (occupancy+FETCH).
//  r7: sk-phase internals invariant ~150us => cost is the serial chain itself.
//  r8: SW grid barrier = ~65us each (1024 pollers on one line = serialized
//      coherence-point service). Kernel boundaries ARE the cheap grid sync.
//  r9: GEMM rewritten: 256^2 tile, 8 waves, BK=64, 2-side LDS(128KB),
//      read-all-frags-then-free-side + counted vmcnt(8) + raw s_barrier
//      (never vmcnt(0) in loop) + XOR bank swizzle (chunk ^= row&7) applied
//      source-side for gload_lds (rule: linear dest, inv-swz source, swz read).

static __device__ __forceinline__ size_t xb_off(int i) {
    return ((size_t)(i >> 1) << 13) + 4096 + ((size_t)(i & 1) << 11);
}
static __device__ __forceinline__ size_t yb_off(int j) {
    return ((size_t)1 << 25) + ((size_t)(j >> 1) << 13) + 4096 + ((size_t)(j & 1) << 11);
}

// ---------------------------------------------------------------------------
// fp32 pair -> packed bf16 (RNE)
// ---------------------------------------------------------------------------
static __device__ __forceinline__ unsigned pk_bf16(float a, float b) {
#if __has_builtin(__builtin_amdgcn_cvt_pk_bf16_f32)
    typedef __bf16 bf16x2 __attribute__((ext_vector_type(2)));
    bf16x2 r = __builtin_amdgcn_cvt_pk_bf16_f32(a, b);
    return __builtin_bit_cast(unsigned, r);
#else
    unsigned ua = __float_as_uint(a), ub = __float_as_uint(b);
    ua += 0x7FFFu + ((ua >> 16) & 1u);
    ub += 0x7FFFu + ((ub >> 16) & 1u);
    return (ua >> 16) | (ub & 0xFFFF0000u);
#endif
}

static __device__ __forceinline__ bf16x8 lds_frag(const unsigned short* p) {
    return __builtin_bit_cast(bf16x8, *(const u16x8*)p);
}

static __device__ __forceinline__ void gload16(const void* g, void* l) {
    __builtin_amdgcn_global_load_lds(
        (const __attribute__((address_space(1))) unsigned int*)g,
        (__attribute__((address_space(3))) unsigned int*)l, 16, 0, 0);
}

// ---------------------------------------------------------------------------
// per-row stats (min, sum, ||a-min||^2) + bf16 conversion into d_out holes.
// Block 0 additionally does init (params, sigma=0, d2max=0, dist=0).
// ---------------------------------------------------------------------------
__global__ __launch_bounds__(256) void rowstats_cvt(
    const float* __restrict__ X, const float* __restrict__ Y,
    unsigned char* __restrict__ outb,
    const int* __restrict__ iters, const int* __restrict__ ipe,
    float* __restrict__ params, float* __restrict__ sigma,
    unsigned int* __restrict__ d2max, float* __restrict__ dist,
    float* __restrict__ mx, float* __restrict__ sx, float* __restrict__ x2,
    float* __restrict__ my, float* __restrict__ sy, float* __restrict__ y2)
{
    const int b = blockIdx.x, tid = threadIdx.x;

    if (b == 0) {
        #pragma unroll 1
        for (int i = tid; i < 3 * M_COLS; i += 256) sigma[i] = 0.0f;
        if (tid == 0) {
            float ramp = 10.0f * (float)ipe[0];
            float rho;
            if (ramp == 0.0f) {
                rho = 1.1f;
            } else {
                float cur = fminf(fmaxf((float)iters[0], 0.0f), ramp);
                float phase = 1.0f - cur / ramp;
                rho = expf(-5.0f * phase * phase) + 0.1f;
            }
            rho = fminf(rho, 1.0f);
            params[0] = rho;
            params[1] = logf(rho) - LOG_M;   // logb = log(rho/M)
            *d2max = 0u;
            *dist = 0.0f;
        }
    }

    const bool isX = b < N_ROWS;
    const int row = isX ? b : b - N_ROWS;
    const float* src = isX ? (X + (size_t)row * K_DIM) : (Y + (size_t)row * K_DIM);
    const float4 v = ((const float4*)src)[tid];

    uint2 p; p.x = pk_bf16(v.x, v.y); p.y = pk_bf16(v.z, v.w);
    size_t off = isX ? xb_off(row) : yb_off(row);
    *(uint2*)(outb + off + (size_t)tid * 8) = p;

    float lmin = fminf(fminf(v.x, v.y), fminf(v.z, v.w));
    float lsum = v.x + v.y + v.z + v.w;
    float lsq  = v.x*v.x + v.y*v.y + v.z*v.z + v.w*v.w;

    __shared__ float rmin[256], rsum[256], rsq[256];
    rmin[tid] = lmin; rsum[tid] = lsum; rsq[tid] = lsq;
    __syncthreads();
    for (int s = 128; s > 0; s >>= 1) {
        if (tid < s) {
            rmin[tid] = fminf(rmin[tid], rmin[tid + s]);
            rsum[tid] += rsum[tid + s];
            rsq[tid]  += rsq[tid + s];
        }
        __syncthreads();
    }
    if (tid == 0) {
        float m = rmin[0], s = rsum[0], q = rsq[0];
        if (isX) { mx[row] = m; sx[row] = s; x2[row] = q - 2.f*m*s + (float)K_DIM*m*m; }
        else     { my[row] = m; sy[row] = s; y2[row] = q - 2.f*m*s + (float)K_DIM*m*m; }
    }
}

// ---------------------------------------------------------------------------
// MFMA GEMM v2: 256x256 tile, 8 waves (2M x 4N, 128x64 per wave), BK=64.
// 2-side LDS double buffer (128 KB), read-all-frags-then-free-side schedule
// with COUNTED vmcnt(8) (never 0 in the loop) across raw s_barriers.
// Race ledger:
//  - tile t lives in side t&1; at tile-t top only tile t+1's 8 loads are
//    newer -> vmcnt(8)+s_barrier => every wave's tile-t loads landed.
//  - all ds_reads of side t&1 complete before the mid-tile lgkmcnt(0)+
//    s_barrier -> STAGE(t+2) into side t&1 issued after is safe; its reads
//    happen only after tile t+2's top vmcnt confirms landing.
//  - write-write on a side: stage(t) landed (tile-t top vmcnt) before
//    stage(t+2) is issued. Tail: t=14 stages nothing; t=15 waits vmcnt(0).
// Bank swizzle: logical (row,chunk16B) stored at slot = chunk ^ (row&7);
// gload_lds keeps a LINEAR dest and the SOURCE address is inverse-swizzled;
// ds_read applies the same XOR -> 2 lanes/slot, conflict-free-ish.
// ---------------------------------------------------------------------------
__global__ __launch_bounds__(512, 2) void gemm_cost_mfma(
    float* __restrict__ gbuf,
    const float* __restrict__ mx, const float* __restrict__ sx, const float* __restrict__ x2,
    const float* __restrict__ my, const float* __restrict__ sy, const float* __restrict__ y2,
    unsigned int* __restrict__ d2max)
{
    __shared__ unsigned short Ash[2][256 * 64];   // 2 x 32 KB
    __shared__ unsigned short Bsh[2][256 * 64];   // 2 x 32 KB
    __shared__ float rmax[512];

    const unsigned char* outb = (const unsigned char*)gbuf;
    const int tid  = threadIdx.x;
    const int lane = tid & 63;
    const int wave = tid >> 6;        // 0..7
    const int wm   = wave >> 2;       // 0..1  (M half)
    const int wn   = wave & 3;        // 0..3  (N quarter)
    const int r16  = lane & 15;
    const int q    = lane >> 4;       // 0..3

    // XCD-aware swizzle (bijective: 256 blocks, 256%8==0).
    const int bid0 = blockIdx.x;
    const int bid  = (bid0 & 7) * 32 + (bid0 >> 3);
    const int i0 = (bid >> 3) * 256, j0 = (bid & 7) * 256;

    // staging: thread covers (row = g*64 + srow, slot = sslot) of a 64-row grp
    const int srow  = tid >> 3;       // 0..63
    const int sslot = tid & 7;
    const int chS   = (sslot ^ (srow & 7)) * 16;   // inverse-swizzled src chunk

    f32x4 acc[8][4];
    #pragma unroll
    for (int u = 0; u < 8; ++u)
        #pragma unroll
        for (int v = 0; v < 4; ++v) acc[u][v] = (f32x4){0.f, 0.f, 0.f, 0.f};

    bf16x8 af[8], bfr[4];

#define STAGE(t2, s) do {                                                      \
        const int kb = (t2) * 128;                                             \
        _Pragma("unroll")                                                      \
        for (int g = 0; g < 4; ++g) {                                          \
            const int rw = g * 64 + srow;                                      \
            gload16(outb + xb_off(i0 + rw) + kb + chS,                         \
                    &Ash[s][g * 4096 + wave * 512]);                           \
            gload16(outb + yb_off(j0 + rw) + kb + chS,                         \
                    &Bsh[s][g * 4096 + wave * 512]);                           \
        }                                                                      \
    } while (0)

#define FRAGS(s, kk) do {                                                      \
        _Pragma("unroll")                                                      \
        for (int mi = 0; mi < 8; ++mi) {                                       \
            const int rA = wm * 128 + mi * 16 + r16;                           \
            af[mi] = lds_frag(&Ash[s][rA * 64 + (((kk)*4 + q) ^ (rA & 7)) * 8]); \
        }                                                                      \
        _Pragma("unroll")                                                      \
        for (int ni = 0; ni < 4; ++ni) {                                       \
            const int rB = wn * 64 + ni * 16 + r16;                            \
            bfr[ni] = lds_frag(&Bsh[s][rB * 64 + (((kk)*4 + q) ^ (rB & 7)) * 8]); \
        }                                                                      \
    } while (0)

#define MMAS() do {                                                            \
        _Pragma("unroll")                                                      \
        for (int mi = 0; mi < 8; ++mi)                                         \
            _Pragma("unroll")                                                  \
            for (int ni = 0; ni < 4; ++ni)                                     \
                acc[mi][ni] = __builtin_amdgcn_mfma_f32_16x16x32_bf16(         \
                    af[mi], bfr[ni], acc[mi][ni], 0, 0, 0);                    \
    } while (0)

    // prologue: tiles 0,1 -> sides 0,1 (16 loads in flight per thread)
    STAGE(0, 0);
    STAGE(1, 1);

    #pragma unroll 1
    for (int t = 0; t < 16; ++t) {
        const int side = t & 1;
        if (t < 15) asm volatile("s_waitcnt vmcnt(8)" ::: "memory");
        else        asm volatile("s_waitcnt vmcnt(0)" ::: "memory");
        __builtin_amdgcn_s_barrier();
        __builtin_amdgcn_sched_barrier(0);

        FRAGS(side, 0);
        asm volatile("s_waitcnt lgkmcnt(0)" ::: "memory");
        __builtin_amdgcn_sched_barrier(0);
        __builtin_amdgcn_s_setprio(1); MMAS(); __builtin_amdgcn_s_setprio(0);

        FRAGS(side, 1);
        asm volatile("s_waitcnt lgkmcnt(0)" ::: "memory");
        __builtin_amdgcn_sched_barrier(0);
        __builtin_amdgcn_s_barrier();            // all reads of this side done
        __builtin_amdgcn_sched_barrier(0);
        if (t <= 13) STAGE(t + 2, side);
        __builtin_amdgcn_s_setprio(1); MMAS(); __builtin_amdgcn_s_setprio(0);
    }

#undef STAGE
#undef FRAGS
#undef MMAS

    // epilogue: C/D 16x16 layout col=lane&15 (j), row=q*4+reg (i)
    _Float16* costh = (_Float16*)gbuf;
    float lmax = 0.0f;
    float myj[4], syj[4], yy[4];
    int jb[4];
    #pragma unroll
    for (int ni = 0; ni < 4; ++ni) {
        jb[ni] = j0 + wn * 64 + ni * 16 + r16;
        myj[ni] = my[jb[ni]]; syj[ni] = sy[jb[ni]]; yy[ni] = y2[jb[ni]];
    }
    #pragma unroll
    for (int mi = 0; mi < 8; ++mi) {
        #pragma unroll
        for (int reg = 0; reg < 4; ++reg) {
            const int i = i0 + wm * 128 + mi * 16 + q * 4 + reg;
            const float mxi = mx[i], sxi = sx[i], xxi = x2[i];
            #pragma unroll
            for (int ni = 0; ni < 4; ++ni) {
                float corr = mxi * syj[ni] + myj[ni] * sxi - (float)K_DIM * mxi * myj[ni];
                float d2 = xxi + yy[ni] - 2.0f * acc[mi][ni][reg] + 2.0f * corr;
                d2 = fmaxf(d2, 0.0f);
                lmax = fmaxf(lmax, d2);
                costh[(size_t)i * 4096 + jb[ni]] = (_Float16)sqrtf(d2);
            }
        }
    }
    rmax[tid] = lmax;
    __syncthreads();
    for (int s = 256; s > 0; s >>= 1) {
        if (tid < s) rmax[tid] = fmaxf(rmax[tid], rmax[tid + s]);
        __syncthreads();
    }
    if (tid == 0) atomicMax(d2max, __float_as_uint(rmax[0]));
}

// ---------------------------------------------------------------------------
// Sinkhorn pass IT (0,1,2): E = exp(-cost*10/cmax) staged in LDS (32 KB,
// 4 blocks/CU). Column partials -> fp16 stores to gpart (no hot atomics).
// (r7 verified — unchanged)
// ---------------------------------------------------------------------------
template<int IT>
__global__ __launch_bounds__(256, 4) void sk_pass(
    const float* __restrict__ outbuf, const float* __restrict__ sigma,
    _Float16* __restrict__ gpart, float* __restrict__ w,
    const float* __restrict__ params, const unsigned int* __restrict__ d2max)
{
    __shared__ _Float16 Esh[RPB * M_COLS];   // 32 KB
    __shared__ float R[RPB][4];
    __shared__ float W[RPB];

    const int tid  = threadIdx.x;
    const int lane = tid & 63;
    const int wave = tid >> 6;
    const int r0   = blockIdx.x * RPB;
    const float logb = params[1];
    const float invC10 = 10.0f * rsqrtf(__uint_as_float(*d2max));

    float u8[8];
    if constexpr (IT == 0) {
        #pragma unroll
        for (int c = 0; c < 8; ++c) u8[c] = 1.0f;
    } else {
        const float* sg = sigma + (IT - 1) * M_COLS;
        const float4 sa = *(const float4*)(sg + 8 * tid);
        const float4 sb = *(const float4*)(sg + 8 * tid + 4);
        u8[0] = (float)N_ROWS / sa.x; u8[1] = (float)N_ROWS / sa.y;
        u8[2] = (float)N_ROWS / sa.z; u8[3] = (float)N_ROWS / sa.w;
        u8[4] = (float)N_ROWS / sb.x; u8[5] = (float)N_ROWS / sb.y;
        u8[6] = (float)N_ROWS / sb.z; u8[7] = (float)N_ROWS / sb.w;
    }

    const _Float16* Cb = (const _Float16*)outbuf;
    float pr[RPB];
    #pragma unroll
    for (int r = 0; r < RPB; ++r) {
        h8 c = __builtin_bit_cast(h8, *(const uint4*)(Cb + (size_t)(r0 + r) * 4096 + 8 * tid));
        h8 e;
        float s = 0.0f;
        #pragma unroll
        for (int k = 0; k < 8; ++k) {
            _Float16 ek = (_Float16)__expf(-(float)c[k] * invC10);
            e[k] = ek;
            s += (float)ek * u8[k];
        }
        *(uint4*)&Esh[r * M_COLS + 8 * tid] = __builtin_bit_cast(uint4, e);
        pr[r] = s;
    }

    #pragma unroll
    for (int r = 0; r < RPB; ++r)
        #pragma unroll
        for (int off = 32; off > 0; off >>= 1)
            pr[r] += __shfl_xor(pr[r], off, 64);

    if (lane == 0)
        #pragma unroll
        for (int r = 0; r < RPB; ++r) R[r][wave] = pr[r];
    __syncthreads();
    if (tid < RPB) {
        float t = R[tid][0] + R[tid][1] + R[tid][2] + R[tid][3];
        float wr = __expf(-LAM * (logb + __logf(t)));
        W[tid] = wr;
        if constexpr (IT == 2) w[r0 + tid] = wr;
    }
    __syncthreads();

    float p[8] = {0.f, 0.f, 0.f, 0.f, 0.f, 0.f, 0.f, 0.f};
    #pragma unroll
    for (int r = 0; r < RPB; ++r) {
        h8 e = __builtin_bit_cast(h8, *(const uint4*)&Esh[r * M_COLS + 8 * tid]);
        const float wr = W[r];
        #pragma unroll
        for (int k = 0; k < 8; ++k) p[k] += (float)e[k] * wr;
    }
    h8 ph;
    #pragma unroll
    for (int k = 0; k < 8; ++k) ph[k] = (_Float16)p[k];
    *(uint4*)(gpart + (size_t)blockIdx.x * M_COLS + 8 * tid) = __builtin_bit_cast(uint4, ph);
}

// ---------------------------------------------------------------------------
// sigma[col] += sum over a 64-row slab of gpart. 128 blocks; atomic depth 16.
// ---------------------------------------------------------------------------
__global__ __launch_bounds__(256) void sk_gred(
    const _Float16* __restrict__ gpart, float* __restrict__ sigma)
{
    const int col = (blockIdx.x & 7) * 256 + threadIdx.x;
    const int b0  = (blockIdx.x >> 3) * (SKB / 16);
    float s = 0.0f;
    #pragma unroll 8
    for (int b = 0; b < SKB / 16; ++b)
        s += (float)gpart[(size_t)(b0 + b) * M_COLS + col];
    atomicAdd(&sigma[col], s);
}

// ---------------------------------------------------------------------------
// flow = E * w_r * u_j / (N*M); dist += sum cn * flow, cn = cost/cmax.
// Cost rows staged in LDS (32 KB, 4 blocks/CU); ONE barrier, then store.
// (r7 verified — unchanged)
// ---------------------------------------------------------------------------
__global__ __launch_bounds__(256, 4) void flow_dist(
    float* __restrict__ outbuf, const float* __restrict__ w,
    const float* __restrict__ sigma2, const unsigned int* __restrict__ d2max,
    float* __restrict__ dist)
{
    __shared__ _Float16 Csh[RPB * M_COLS];   // 32 KB
    __shared__ float W[RPB];
    __shared__ float red[256];

    const int tid = threadIdx.x;
    const int r0  = blockIdx.x * RPB;
    const float invNM = 1.0f / ((float)N_ROWS * (float)M_COLS);
    const float invC10 = 10.0f * rsqrtf(__uint_as_float(*d2max));
    const float inv01  = 0.1f * invC10;          // = 1/cmax
    const _Float16* Cb = (const _Float16*)outbuf;

    #pragma unroll
    for (int r = 0; r < RPB; ++r) {
        uint4 cv = *(const uint4*)(Cb + (size_t)(r0 + r) * 4096 + 8 * tid);
        *(uint4*)&Csh[r * M_COLS + 8 * tid] = cv;
    }

    if (tid < RPB) W[tid] = w[r0 + tid];

    const float4 sA = *(const float4*)(sigma2 + 8 * tid);
    const float4 sB = *(const float4*)(sigma2 + 8 * tid + 4);
    float u8[8];
    u8[0] = (float)N_ROWS / sA.x; u8[1] = (float)N_ROWS / sA.y;
    u8[2] = (float)N_ROWS / sA.z; u8[3] = (float)N_ROWS / sA.w;
    u8[4] = (float)N_ROWS / sB.x; u8[5] = (float)N_ROWS / sB.y;
    u8[6] = (float)N_ROWS / sB.z; u8[7] = (float)N_ROWS / sB.w;

    __syncthreads();

    float local = 0.0f;
    #pragma unroll
    for (int r = 0; r < RPB; ++r) {
        h8 c = __builtin_bit_cast(h8, *(const uint4*)&Csh[r * M_COLS + 8 * tid]);
        const float wr = W[r];
        float fl[8];
        #pragma unroll
        for (int k = 0; k < 8; ++k) {
            float cst = (float)c[k];
            float e = __expf(-cst * invC10);
            float o = e * wr * u8[k] * invNM;
            fl[k] = o;
            local += (cst * inv01) * o;
        }
        float4 o0 = {fl[0], fl[1], fl[2], fl[3]};
        float4 o1 = {fl[4], fl[5], fl[6], fl[7]};
        float* frow = outbuf + (size_t)(r0 + r) * M_COLS + 8 * tid;
        *(float4*)frow = o0;
        *(float4*)(frow + 4) = o1;
    }

    red[tid] = local;
    __syncthreads();
    for (int s = 128; s > 0; s >>= 1) {
        if (tid < s) red[tid] += red[tid + s];
        __syncthreads();
    }
    if (tid == 0) atomicAdd(dist, red[0]);
}

// ---------------------------------------------------------------------------
extern "C" void kernel_launch(void* const* d_in, const int* in_sizes, int n_in,
                              void* d_out, int out_size, void* d_ws, size_t ws_size,
                              hipStream_t stream)
{
    const float* x     = (const float*)d_in[0];
    const float* y     = (const float*)d_in[1];
    const int*   iters = (const int*)d_in[2];
    const int*   ipe   = (const int*)d_in[3];
    float* out = (float*)d_out;
    float* ws  = (float*)d_ws;

    // ws layout (floats): ~4.2 MB total
    float*        params = ws;                       // [0]=rho [1]=logb
    unsigned int* d2max  = (unsigned int*)(ws + 8);
    float* w     = ws + 16;                          // 8192
    float* sigma = w + N_ROWS;                       // 3 * 2048 (zeroed by rowstats blk0)
    float* mx = sigma + 3 * M_COLS;                  // 8192
    float* sx = mx + N_ROWS;                         // 8192
    float* x2 = sx + N_ROWS;                         // 8192
    float* my = x2 + N_ROWS;                         // 2048
    float* sy = my + M_COLS;                         // 2048
    float* y2 = sy + M_COLS;                         // 2048
    _Float16* gpart = (_Float16*)(y2 + M_COLS);      // 1024*2048 fp16 = 4 MB

    float* sigma0 = sigma;
    float* sigma1 = sigma + M_COLS;
    float* sigma2 = sigma + 2 * M_COLS;

    float* dist = out + NM;

    rowstats_cvt<<<N_ROWS + M_COLS, 256, 0, stream>>>(
        x, y, (unsigned char*)out, iters, ipe, params, sigma, d2max, dist,
        mx, sx, x2, my, sy, y2);
    gemm_cost_mfma<<<(N_ROWS / 256) * (M_COLS / 256), 512, 0, stream>>>(
        out, mx, sx, x2, my, sy, y2, d2max);

    sk_pass<0><<<SKB, 256, 0, stream>>>(out, sigma, gpart, w, params, d2max);
    sk_gred<<<128, 256, 0, stream>>>(gpart, sigma0);
    sk_pass<1><<<SKB, 256, 0, stream>>>(out, sigma, gpart, w, params, d2max);
    sk_gred<<<128, 256, 0, stream>>>(gpart, sigma1);
    sk_pass<2><<<SKB, 256, 0, stream>>>(out, sigma, gpart, w, params, d2max);
    sk_gred<<<128, 256, 0, stream>>>(gpart, sigma2);

    flow_dist<<<SKB, 256, 0, stream>>>(out, w, sigma2, d2max, dist);
}

// Round 10
// 205.921 us; speedup vs baseline: 3.3807x; 1.0137x over previous
//
#include <hip/hip_runtime.h>
#include <math.h>

// Problem constants
#define N_ROWS 8192
#define M_COLS 2048
#define K_DIM  1024
#define NM     ((size_t)N_ROWS * M_COLS)

#define LAM       0.9090909090909091f         // GAMMA/(GAMMA+EPS)
#define LOG_M     7.624618986159398f          // log(2048)

#define SKB 1024                               // sinkhorn blocks (4/CU resident)
#define RPB (N_ROWS / SKB)                     // 8 rows per block

typedef __bf16 bf16x8 __attribute__((ext_vector_type(8)));
typedef float  f32x4  __attribute__((ext_vector_type(4)));
typedef unsigned short u16x8 __attribute__((ext_vector_type(8)));
typedef _Float16 h8 __attribute__((ext_vector_type(8)));

// d_out memory map (64 MB):
//   row r (r<8192): bytes [r*8192, r*8192+4096)  = cost fp16 row r (2048 halves)
//                   bytes [r*8192+4096, r*8192+8192) = "hole"
//   Xb bf16 row i (16 MB): hole i>>1, slot i&1  -> byte (i>>1)*8192 + 4096 + (i&1)*2048
//   Yb bf16 row j ( 4 MB): hole 4096+(j>>1)     -> byte 32MB + (j>>1)*8192 + 4096 + (j&1)*2048
//
// LESSONS LEDGER:
//  r4: same-line fp32 atomicAdds at depth 512 = ~120us serialized RMWs.
//  r6: counted-vmcnt 3-buffer at 128^2/BK=32 regresses (occupancy+FETCH).
//  r7: sk-phase internals invariant ~150us => cost is the serial chain itself.
//  r8: SW grid barrier = ~65us each. Kernel boundaries ARE the cheap grid sync.
//  r9: 256^2/8-wave/BK=64 GEMM + source-side XOR swizzle: conflicts 4.19M -> 0,
//      57.4 -> 49.7us. vmcnt(8) counted pipeline verified race-free.
//  r10: removed mid-phase lgkm(0)+sched_barrier pins (m141 lesson: explicit
//      order-pinning defeats the compiler's fine-grained lgkmcnt interleave).
//      Only asm anchors kept: top vmcnt+barrier, mid lgkm(0)+barrier+schedbar.

static __device__ __forceinline__ size_t xb_off(int i) {
    return ((size_t)(i >> 1) << 13) + 4096 + ((size_t)(i & 1) << 11);
}
static __device__ __forceinline__ size_t yb_off(int j) {
    return ((size_t)1 << 25) + ((size_t)(j >> 1) << 13) + 4096 + ((size_t)(j & 1) << 11);
}

// ---------------------------------------------------------------------------
// fp32 pair -> packed bf16 (RNE)
// ---------------------------------------------------------------------------
static __device__ __forceinline__ unsigned pk_bf16(float a, float b) {
#if __has_builtin(__builtin_amdgcn_cvt_pk_bf16_f32)
    typedef __bf16 bf16x2 __attribute__((ext_vector_type(2)));
    bf16x2 r = __builtin_amdgcn_cvt_pk_bf16_f32(a, b);
    return __builtin_bit_cast(unsigned, r);
#else
    unsigned ua = __float_as_uint(a), ub = __float_as_uint(b);
    ua += 0x7FFFu + ((ua >> 16) & 1u);
    ub += 0x7FFFu + ((ub >> 16) & 1u);
    return (ua >> 16) | (ub & 0xFFFF0000u);
#endif
}

static __device__ __forceinline__ bf16x8 lds_frag(const unsigned short* p) {
    return __builtin_bit_cast(bf16x8, *(const u16x8*)p);
}

static __device__ __forceinline__ void gload16(const void* g, void* l) {
    __builtin_amdgcn_global_load_lds(
        (const __attribute__((address_space(1))) unsigned int*)g,
        (__attribute__((address_space(3))) unsigned int*)l, 16, 0, 0);
}

// ---------------------------------------------------------------------------
// per-row stats (min, sum, ||a-min||^2) + bf16 conversion into d_out holes.
// Block 0 additionally does init (params, sigma=0, d2max=0, dist=0).
// ---------------------------------------------------------------------------
__global__ __launch_bounds__(256) void rowstats_cvt(
    const float* __restrict__ X, const float* __restrict__ Y,
    unsigned char* __restrict__ outb,
    const int* __restrict__ iters, const int* __restrict__ ipe,
    float* __restrict__ params, float* __restrict__ sigma,
    unsigned int* __restrict__ d2max, float* __restrict__ dist,
    float* __restrict__ mx, float* __restrict__ sx, float* __restrict__ x2,
    float* __restrict__ my, float* __restrict__ sy, float* __restrict__ y2)
{
    const int b = blockIdx.x, tid = threadIdx.x;

    if (b == 0) {
        #pragma unroll 1
        for (int i = tid; i < 3 * M_COLS; i += 256) sigma[i] = 0.0f;
        if (tid == 0) {
            float ramp = 10.0f * (float)ipe[0];
            float rho;
            if (ramp == 0.0f) {
                rho = 1.1f;
            } else {
                float cur = fminf(fmaxf((float)iters[0], 0.0f), ramp);
                float phase = 1.0f - cur / ramp;
                rho = expf(-5.0f * phase * phase) + 0.1f;
            }
            rho = fminf(rho, 1.0f);
            params[0] = rho;
            params[1] = logf(rho) - LOG_M;   // logb = log(rho/M)
            *d2max = 0u;
            *dist = 0.0f;
        }
    }

    const bool isX = b < N_ROWS;
    const int row = isX ? b : b - N_ROWS;
    const float* src = isX ? (X + (size_t)row * K_DIM) : (Y + (size_t)row * K_DIM);
    const float4 v = ((const float4*)src)[tid];

    uint2 p; p.x = pk_bf16(v.x, v.y); p.y = pk_bf16(v.z, v.w);
    size_t off = isX ? xb_off(row) : yb_off(row);
    *(uint2*)(outb + off + (size_t)tid * 8) = p;

    float lmin = fminf(fminf(v.x, v.y), fminf(v.z, v.w));
    float lsum = v.x + v.y + v.z + v.w;
    float lsq  = v.x*v.x + v.y*v.y + v.z*v.z + v.w*v.w;

    __shared__ float rmin[256], rsum[256], rsq[256];
    rmin[tid] = lmin; rsum[tid] = lsum; rsq[tid] = lsq;
    __syncthreads();
    for (int s = 128; s > 0; s >>= 1) {
        if (tid < s) {
            rmin[tid] = fminf(rmin[tid], rmin[tid + s]);
            rsum[tid] += rsum[tid + s];
            rsq[tid]  += rsq[tid + s];
        }
        __syncthreads();
    }
    if (tid == 0) {
        float m = rmin[0], s = rsum[0], q = rsq[0];
        if (isX) { mx[row] = m; sx[row] = s; x2[row] = q - 2.f*m*s + (float)K_DIM*m*m; }
        else     { my[row] = m; sy[row] = s; y2[row] = q - 2.f*m*s + (float)K_DIM*m*m; }
    }
}

// ---------------------------------------------------------------------------
// MFMA GEMM v2.1: 256x256 tile, 8 waves (2M x 4N, 128x64/wave), BK=64.
// 2-side LDS double buffer (128 KB), counted vmcnt(8), XOR bank swizzle.
// Race ledger (unchanged from r9, verified):
//  - tile t in side t&1; at tile-t top only tile t+1's 8 loads are newer
//    -> vmcnt(8)+s_barrier => tile-t loads landed for every wave.
//  - all ds_reads of the side complete before mid lgkm(0)+s_barrier ->
//    STAGE(t+2) into it afterwards is safe (sched_barrier pins STAGE below).
//  - loads cannot hoist above the top barrier (sched_barrier(0)) nor sink
//    below the mid lgkm asm (memory clobber). MFMAs are register-only and
//    gated by compiler-inserted waits on their frag registers.
// NEW in v2.1: no lgkm/sched pins between FRAGS and MMAS -> the compiler
// interleaves FRAGS1's ds_reads into MMAS0 with counted lgkmcnt (m141/m97).
// ---------------------------------------------------------------------------
__global__ __launch_bounds__(512, 2) void gemm_cost_mfma(
    float* __restrict__ gbuf,
    const float* __restrict__ mx, const float* __restrict__ sx, const float* __restrict__ x2,
    const float* __restrict__ my, const float* __restrict__ sy, const float* __restrict__ y2,
    unsigned int* __restrict__ d2max)
{
    __shared__ unsigned short Ash[2][256 * 64];   // 2 x 32 KB
    __shared__ unsigned short Bsh[2][256 * 64];   // 2 x 32 KB
    __shared__ float rmax[512];

    const unsigned char* outb = (const unsigned char*)gbuf;
    const int tid  = threadIdx.x;
    const int lane = tid & 63;
    const int wave = tid >> 6;        // 0..7
    const int wm   = wave >> 2;       // 0..1  (M half)
    const int wn   = wave & 3;        // 0..3  (N quarter)
    const int r16  = lane & 15;
    const int q    = lane >> 4;       // 0..3

    // XCD-aware swizzle (bijective: 256 blocks, 256%8==0).
    const int bid0 = blockIdx.x;
    const int bid  = (bid0 & 7) * 32 + (bid0 >> 3);
    const int i0 = (bid >> 3) * 256, j0 = (bid & 7) * 256;

    // staging: thread covers (row = g*64 + srow, slot = sslot) of a 64-row grp
    const int srow  = tid >> 3;       // 0..63
    const int sslot = tid & 7;
    const int chS   = (sslot ^ (srow & 7)) * 16;   // inverse-swizzled src chunk

    f32x4 acc[8][4];
    #pragma unroll
    for (int u = 0; u < 8; ++u)
        #pragma unroll
        for (int v = 0; v < 4; ++v) acc[u][v] = (f32x4){0.f, 0.f, 0.f, 0.f};

#define STAGE(t2, s) do {                                                      \
        const int kb = (t2) * 128;                                             \
        _Pragma("unroll")                                                      \
        for (int g = 0; g < 4; ++g) {                                          \
            const int rw = g * 64 + srow;                                      \
            gload16(outb + xb_off(i0 + rw) + kb + chS,                         \
                    &Ash[s][g * 4096 + wave * 512]);                           \
            gload16(outb + yb_off(j0 + rw) + kb + chS,                         \
                    &Bsh[s][g * 4096 + wave * 512]);                           \
        }                                                                      \
    } while (0)

#define FRAGS(s, kk, AF, BF) do {                                              \
        _Pragma("unroll")                                                      \
        for (int mi = 0; mi < 8; ++mi) {                                       \
            const int rA = wm * 128 + mi * 16 + r16;                           \
            AF[mi] = lds_frag(&Ash[s][rA * 64 + (((kk)*4 + q) ^ (rA & 7)) * 8]); \
        }                                                                      \
        _Pragma("unroll")                                                      \
        for (int ni = 0; ni < 4; ++ni) {                                       \
            const int rB = wn * 64 + ni * 16 + r16;                            \
            BF[ni] = lds_frag(&Bsh[s][rB * 64 + (((kk)*4 + q) ^ (rB & 7)) * 8]); \
        }                                                                      \
    } while (0)

#define MMAS(AF, BF) do {                                                      \
        _Pragma("unroll")                                                      \
        for (int mi = 0; mi < 8; ++mi)                                         \
            _Pragma("unroll")                                                  \
            for (int ni = 0; ni < 4; ++ni)                                     \
                acc[mi][ni] = __builtin_amdgcn_mfma_f32_16x16x32_bf16(         \
                    AF[mi], BF[ni], acc[mi][ni], 0, 0, 0);                     \
    } while (0)

    // prologue: tiles 0,1 -> sides 0,1 (16 loads in flight per thread)
    STAGE(0, 0);
    STAGE(1, 1);

    #pragma unroll 1
    for (int t = 0; t < 16; ++t) {
        const int side = t & 1;
        if (t < 15) asm volatile("s_waitcnt vmcnt(8)" ::: "memory");
        else        asm volatile("s_waitcnt vmcnt(0)" ::: "memory");
        __builtin_amdgcn_s_barrier();
        __builtin_amdgcn_sched_barrier(0);

        bf16x8 a0[8], b0[4], a1[8], b1[4];
        FRAGS(side, 0, a0, b0);
        __builtin_amdgcn_s_setprio(1);
        MMAS(a0, b0);                 // compiler interleaves the a1/b1 reads here
        FRAGS(side, 1, a1, b1);
        __builtin_amdgcn_s_setprio(0);

        asm volatile("s_waitcnt lgkmcnt(0)" ::: "memory");   // side reads done
        __builtin_amdgcn_s_barrier();
        __builtin_amdgcn_sched_barrier(0);                   // pin STAGE below
        if (t <= 13) STAGE(t + 2, side);
        __builtin_amdgcn_s_setprio(1);
        MMAS(a1, b1);
        __builtin_amdgcn_s_setprio(0);
    }

#undef STAGE
#undef FRAGS
#undef MMAS

    // epilogue: C/D 16x16 layout col=lane&15 (j), row=q*4+reg (i)
    _Float16* costh = (_Float16*)gbuf;
    float lmax = 0.0f;
    float myj[4], syj[4], yy[4];
    int jb[4];
    #pragma unroll
    for (int ni = 0; ni < 4; ++ni) {
        jb[ni] = j0 + wn * 64 + ni * 16 + r16;
        myj[ni] = my[jb[ni]]; syj[ni] = sy[jb[ni]]; yy[ni] = y2[jb[ni]];
    }
    #pragma unroll
    for (int mi = 0; mi < 8; ++mi) {
        #pragma unroll
        for (int reg = 0; reg < 4; ++reg) {
            const int i = i0 + wm * 128 + mi * 16 + q * 4 + reg;
            const float mxi = mx[i], sxi = sx[i], xxi = x2[i];
            #pragma unroll
            for (int ni = 0; ni < 4; ++ni) {
                float corr = mxi * syj[ni] + myj[ni] * sxi - (float)K_DIM * mxi * myj[ni];
                float d2 = xxi + yy[ni] - 2.0f * acc[mi][ni][reg] + 2.0f * corr;
                d2 = fmaxf(d2, 0.0f);
                lmax = fmaxf(lmax, d2);
                costh[(size_t)i * 4096 + jb[ni]] = (_Float16)sqrtf(d2);
            }
        }
    }
    rmax[tid] = lmax;
    __syncthreads();
    for (int s = 256; s > 0; s >>= 1) {
        if (tid < s) rmax[tid] = fmaxf(rmax[tid], rmax[tid + s]);
        __syncthreads();
    }
    if (tid == 0) atomicMax(d2max, __float_as_uint(rmax[0]));
}

// ---------------------------------------------------------------------------
// Sinkhorn pass IT (0,1,2): E = exp(-cost*10/cmax) staged in LDS (32 KB,
// 4 blocks/CU). Column partials -> fp16 stores to gpart (no hot atomics).
// (r7 verified — unchanged)
// ---------------------------------------------------------------------------
template<int IT>
__global__ __launch_bounds__(256, 4) void sk_pass(
    const float* __restrict__ outbuf, const float* __restrict__ sigma,
    _Float16* __restrict__ gpart, float* __restrict__ w,
    const float* __restrict__ params, const unsigned int* __restrict__ d2max)
{
    __shared__ _Float16 Esh[RPB * M_COLS];   // 32 KB
    __shared__ float R[RPB][4];
    __shared__ float W[RPB];

    const int tid  = threadIdx.x;
    const int lane = tid & 63;
    const int wave = tid >> 6;
    const int r0   = blockIdx.x * RPB;
    const float logb = params[1];
    const float invC10 = 10.0f * rsqrtf(__uint_as_float(*d2max));

    float u8[8];
    if constexpr (IT == 0) {
        #pragma unroll
        for (int c = 0; c < 8; ++c) u8[c] = 1.0f;
    } else {
        const float* sg = sigma + (IT - 1) * M_COLS;
        const float4 sa = *(const float4*)(sg + 8 * tid);
        const float4 sb = *(const float4*)(sg + 8 * tid + 4);
        u8[0] = (float)N_ROWS / sa.x; u8[1] = (float)N_ROWS / sa.y;
        u8[2] = (float)N_ROWS / sa.z; u8[3] = (float)N_ROWS / sa.w;
        u8[4] = (float)N_ROWS / sb.x; u8[5] = (float)N_ROWS / sb.y;
        u8[6] = (float)N_ROWS / sb.z; u8[7] = (float)N_ROWS / sb.w;
    }

    const _Float16* Cb = (const _Float16*)outbuf;
    float pr[RPB];
    #pragma unroll
    for (int r = 0; r < RPB; ++r) {
        h8 c = __builtin_bit_cast(h8, *(const uint4*)(Cb + (size_t)(r0 + r) * 4096 + 8 * tid));
        h8 e;
        float s = 0.0f;
        #pragma unroll
        for (int k = 0; k < 8; ++k) {
            _Float16 ek = (_Float16)__expf(-(float)c[k] * invC10);
            e[k] = ek;
            s += (float)ek * u8[k];
        }
        *(uint4*)&Esh[r * M_COLS + 8 * tid] = __builtin_bit_cast(uint4, e);
        pr[r] = s;
    }

    #pragma unroll
    for (int r = 0; r < RPB; ++r)
        #pragma unroll
        for (int off = 32; off > 0; off >>= 1)
            pr[r] += __shfl_xor(pr[r], off, 64);

    if (lane == 0)
        #pragma unroll
        for (int r = 0; r < RPB; ++r) R[r][wave] = pr[r];
    __syncthreads();
    if (tid < RPB) {
        float t = R[tid][0] + R[tid][1] + R[tid][2] + R[tid][3];
        float wr = __expf(-LAM * (logb + __logf(t)));
        W[tid] = wr;
        if constexpr (IT == 2) w[r0 + tid] = wr;
    }
    __syncthreads();

    float p[8] = {0.f, 0.f, 0.f, 0.f, 0.f, 0.f, 0.f, 0.f};
    #pragma unroll
    for (int r = 0; r < RPB; ++r) {
        h8 e = __builtin_bit_cast(h8, *(const uint4*)&Esh[r * M_COLS + 8 * tid]);
        const float wr = W[r];
        #pragma unroll
        for (int k = 0; k < 8; ++k) p[k] += (float)e[k] * wr;
    }
    h8 ph;
    #pragma unroll
    for (int k = 0; k < 8; ++k) ph[k] = (_Float16)p[k];
    *(uint4*)(gpart + (size_t)blockIdx.x * M_COLS + 8 * tid) = __builtin_bit_cast(uint4, ph);
}

// ---------------------------------------------------------------------------
// sigma[col] += sum over a 64-row slab of gpart. 128 blocks; atomic depth 16.
// ---------------------------------------------------------------------------
__global__ __launch_bounds__(256) void sk_gred(
    const _Float16* __restrict__ gpart, float* __restrict__ sigma)
{
    const int col = (blockIdx.x & 7) * 256 + threadIdx.x;
    const int b0  = (blockIdx.x >> 3) * (SKB / 16);
    float s = 0.0f;
    #pragma unroll 8
    for (int b = 0; b < SKB / 16; ++b)
        s += (float)gpart[(size_t)(b0 + b) * M_COLS + col];
    atomicAdd(&sigma[col], s);
}

// ---------------------------------------------------------------------------
// flow = E * w_r * u_j / (N*M); dist += sum cn * flow, cn = cost/cmax.
// Cost rows staged in LDS (32 KB, 4 blocks/CU); ONE barrier, then store.
// (r7 verified — unchanged)
// ---------------------------------------------------------------------------
__global__ __launch_bounds__(256, 4) void flow_dist(
    float* __restrict__ outbuf, const float* __restrict__ w,
    const float* __restrict__ sigma2, const unsigned int* __restrict__ d2max,
    float* __restrict__ dist)
{
    __shared__ _Float16 Csh[RPB * M_COLS];   // 32 KB
    __shared__ float W[RPB];
    __shared__ float red[256];

    const int tid = threadIdx.x;
    const int r0  = blockIdx.x * RPB;
    const float invNM = 1.0f / ((float)N_ROWS * (float)M_COLS);
    const float invC10 = 10.0f * rsqrtf(__uint_as_float(*d2max));
    const float inv01  = 0.1f * invC10;          // = 1/cmax
    const _Float16* Cb = (const _Float16*)outbuf;

    #pragma unroll
    for (int r = 0; r < RPB; ++r) {
        uint4 cv = *(const uint4*)(Cb + (size_t)(r0 + r) * 4096 + 8 * tid);
        *(uint4*)&Csh[r * M_COLS + 8 * tid] = cv;
    }

    if (tid < RPB) W[tid] = w[r0 + tid];

    const float4 sA = *(const float4*)(sigma2 + 8 * tid);
    const float4 sB = *(const float4*)(sigma2 + 8 * tid + 4);
    float u8[8];
    u8[0] = (float)N_ROWS / sA.x; u8[1] = (float)N_ROWS / sA.y;
    u8[2] = (float)N_ROWS / sA.z; u8[3] = (float)N_ROWS / sA.w;
    u8[4] = (float)N_ROWS / sB.x; u8[5] = (float)N_ROWS / sB.y;
    u8[6] = (float)N_ROWS / sB.z; u8[7] = (float)N_ROWS / sB.w;

    __syncthreads();

    float local = 0.0f;
    #pragma unroll
    for (int r = 0; r < RPB; ++r) {
        h8 c = __builtin_bit_cast(h8, *(const uint4*)&Csh[r * M_COLS + 8 * tid]);
        const float wr = W[r];
        float fl[8];
        #pragma unroll
        for (int k = 0; k < 8; ++k) {
            float cst = (float)c[k];
            float e = __expf(-cst * invC10);
            float o = e * wr * u8[k] * invNM;
            fl[k] = o;
            local += (cst * inv01) * o;
        }
        float4 o0 = {fl[0], fl[1], fl[2], fl[3]};
        float4 o1 = {fl[4], fl[5], fl[6], fl[7]};
        float* frow = outbuf + (size_t)(r0 + r) * M_COLS + 8 * tid;
        *(float4*)frow = o0;
        *(float4*)(frow + 4) = o1;
    }

    red[tid] = local;
    __syncthreads();
    for (int s = 128; s > 0; s >>= 1) {
        if (tid < s) red[tid] += red[tid + s];
        __syncthreads();
    }
    if (tid == 0) atomicAdd(dist, red[0]);
}

// ---------------------------------------------------------------------------
extern "C" void kernel_launch(void* const* d_in, const int* in_sizes, int n_in,
                              void* d_out, int out_size, void* d_ws, size_t ws_size,
                              hipStream_t stream)
{
    const float* x     = (const float*)d_in[0];
    const float* y     = (const float*)d_in[1];
    const int*   iters = (const int*)d_in[2];
    const int*   ipe   = (const int*)d_in[3];
    float* out = (float*)d_out;
    float* ws  = (float*)d_ws;

    // ws layout (floats): ~4.2 MB total
    float*        params = ws;                       // [0]=rho [1]=logb
    unsigned int* d2max  = (unsigned int*)(ws + 8);
    float* w     = ws + 16;                          // 8192
    float* sigma = w + N_ROWS;                       // 3 * 2048 (zeroed by rowstats blk0)
    float* mx = sigma + 3 * M_COLS;                  // 8192
    float* sx = mx + N_ROWS;                         // 8192
    float* x2 = sx + N_ROWS;                         // 8192
    float* my = x2 + N_ROWS;                         // 2048
    float* sy = my + M_COLS;                         // 2048
    float* y2 = sy + M_COLS;                         // 2048
    _Float16* gpart = (_Float16*)(y2 + M_COLS);      // 1024*2048 fp16 = 4 MB

    float* sigma0 = sigma;
    float* sigma1 = sigma + M_COLS;
    float* sigma2 = sigma + 2 * M_COLS;

    float* dist = out + NM;

    rowstats_cvt<<<N_ROWS + M_COLS, 256, 0, stream>>>(
        x, y, (unsigned char*)out, iters, ipe, params, sigma, d2max, dist,
        mx, sx, x2, my, sy, y2);
    gemm_cost_mfma<<<(N_ROWS / 256) * (M_COLS / 256), 512, 0, stream>>>(
        out, mx, sx, x2, my, sy, y2, d2max);

    sk_pass<0><<<SKB, 256, 0, stream>>>(out, sigma, gpart, w, params, d2max);
    sk_gred<<<128, 256, 0, stream>>>(gpart, sigma0);
    sk_pass<1><<<SKB, 256, 0, stream>>>(out, sigma, gpart, w, params, d2max);
    sk_gred<<<128, 256, 0, stream>>>(gpart, sigma1);
    sk_pass<2><<<SKB, 256, 0, stream>>>(out, sigma, gpart, w, params, d2max);
    sk_gred<<<128, 256, 0, stream>>>(gpart, sigma2);

    flow_dist<<<SKB, 256, 0, stream>>>(out, w, sigma2, d2max, dist);
}